// Round 11
// baseline (908.305 us; speedup 1.0000x reference)
//
#include <hip/hip_runtime.h>
#include <hip/hip_cooperative_groups.h>

namespace cg = cooperative_groups;

#define N_NODES   50000
#define HID       64
#define N_GRAPHS  128
#define N_CLASSES 10
#define NP        196           // partitions of 256 nodes (196*256 = 50176)
#define EPA       4096          // edges per bucket chunk
#define PCAP      8192          // per-partition capacity in packed[] (>20 sigma)
#define NCVT      3125          // cvt units: 50000*16/256
#define NVL       1563          // layer units: ceil(50000/32)

typedef __attribute__((ext_vector_type(8))) short short8;
typedef __attribute__((ext_vector_type(4))) float f32x4;

__device__ __forceinline__ unsigned bf16rne(float f) {
    unsigned u = __float_as_uint(f);
    return (u + 0x7fffu + ((u >> 16) & 1u)) >> 16;
}
__device__ __forceinline__ unsigned pack_bf16x2(float lo, float hi) {
    return bf16rne(lo) | (bf16rne(hi) << 16);
}

struct MegaArgs {
    const float* x; const int* src; const int* dst; const int* batch;
    const float* W1r; const float* b1; const float* W1o;
    const float* W2r; const float* b2; const float* W2o;
    const float* W3r; const float* b3; const float* W3o;
    const float* Wl; const float* bl;
    unsigned short* xb; unsigned short* h1; unsigned short* h2;
    unsigned* packed; unsigned short* csr; int* offsets; int* gcursor;
    float* sums; int* gstart; float* out; int E; int nchunk;
};

// ---- fused layer phase: r7-proven 32-node unit, wave-pair MFMA ----------
// smem: wfrag flat [2][4][2][4][16] short8 @0 (16KB), agg [32][72] @16384.
__device__ __noinline__ void layer_phase(char* smem,
    const unsigned short* hin, const int* offsets, const unsigned short* csr_src,
    const float* Wrel, const float* bias, const float* Wroot,
    unsigned short* hout, const int* batch, float* sums,
    int relu, int pool) {
    short8* wfrag = (short8*)smem;
    unsigned short (*agg_lds)[72] = (unsigned short (*)[72])(smem + 16384);
    const int tid = threadIdx.x;
    const int w = tid >> 6, lane = tid & 63;

    // stage weight fragments ONCE per phase (same for all virtual blocks)
    for (int f = tid; f < 1024; f += 256) {
        int m = f >> 9, r = f & 511;
        int t = r >> 7, s = (r >> 6) & 1, q = (r >> 4) & 3, c = r & 15;
        const float* W = m ? Wroot : Wrel;
        const float4* pw = (const float4*)(W + (t * 16 + c) * 64 + s * 32 + q * 8);
        float4 v0 = pw[0], v1 = pw[1];
        short8 fr;
        fr[0] = (short)bf16rne(v0.x); fr[1] = (short)bf16rne(v0.y);
        fr[2] = (short)bf16rne(v0.z); fr[3] = (short)bf16rne(v0.w);
        fr[4] = (short)bf16rne(v1.x); fr[5] = (short)bf16rne(v1.y);
        fr[6] = (short)bf16rne(v1.z); fr[7] = (short)bf16rne(v1.w);
        wfrag[(((m * 4 + t) * 2 + s) * 4 + q) * 16 + c] = fr;
    }

    for (int vb = blockIdx.x; vb < NVL; vb += gridDim.x) {
        __syncthreads();                   // wfrag staged / agg_lds free
        const int g0 = vb * 32;

        // ---- gather: each wave owns 8 nodes (r5/r7-proven body) ----
        {
            const int rg = lane >> 3;      // row group: 8 rows per load instr
            const int cg = lane & 7;       // channel group: 8 ch (16 B)
            const int nb = g0 + w * 8;
            int myoff = (lane < 9) ? offsets[min(nb + lane, N_NODES)] : 0;
            for (int i = 0; i < 8; ++i) {
                const int beg = __shfl(myoff, i), end = __shfl(myoff, i + 1);
                float acc[8] = {0.f, 0.f, 0.f, 0.f, 0.f, 0.f, 0.f, 0.f};
                for (int base = beg; base < end; base += 64) {
                    int cnt = min(64, end - base);
                    int sidx = (base + lane < end) ? (int)csr_src[base + lane] : 0;
                    for (int kb = 0; kb < cnt; kb += 32) {
                        uint4 u[4];
#pragma unroll
                        for (int p = 0; p < 4; ++p) {
                            int e = kb + 8 * p + rg;
                            int r = __shfl(sidx, e);
                            u[p] = (e < cnt) ? *((const uint4*)(hin + (size_t)r * 64) + cg)
                                             : make_uint4(0u, 0u, 0u, 0u);
                        }
#pragma unroll
                        for (int p = 0; p < 4; ++p) {
                            acc[0] += __uint_as_float(u[p].x << 16);
                            acc[1] += __uint_as_float(u[p].x & 0xffff0000u);
                            acc[2] += __uint_as_float(u[p].y << 16);
                            acc[3] += __uint_as_float(u[p].y & 0xffff0000u);
                            acc[4] += __uint_as_float(u[p].z << 16);
                            acc[5] += __uint_as_float(u[p].z & 0xffff0000u);
                            acc[6] += __uint_as_float(u[p].w << 16);
                            acc[7] += __uint_as_float(u[p].w & 0xffff0000u);
                        }
                    }
                }
#pragma unroll
                for (int m = 8; m <= 32; m <<= 1)
#pragma unroll
                    for (int j = 0; j < 8; ++j)
                        acc[j] += __shfl_xor(acc[j], m);
                if (rg == 0) {
                    uint4 o;
                    o.x = pack_bf16x2(acc[0], acc[1]);
                    o.y = pack_bf16x2(acc[2], acc[3]);
                    o.z = pack_bf16x2(acc[4], acc[5]);
                    o.w = pack_bf16x2(acc[6], acc[7]);
                    *((uint4*)&agg_lds[w * 8 + i][cg * 8]) = o;
                }
            }
        }

        __syncthreads();                   // cross-wave agg ready

        // ---- linear: wave-pair shares A, splits output channels ----
        const int ng = w >> 1;
        const int th = w & 1;
        const int q = lane >> 4, c = lane & 15;
        const int n0 = g0 + ng * 16;

        short8 a_agg[2], a_x[2];
#pragma unroll
        for (int s = 0; s < 2; ++s) {
            a_agg[s] = *(const short8*)&agg_lds[ng * 16 + c][s * 32 + q * 8];
            a_x[s]   = *(const short8*)(hin + (size_t)min(n0 + c, N_NODES - 1) * 64 + s * 32 + q * 8);
        }

        f32x4 acc4[2];
#pragma unroll
        for (int tt = 0; tt < 2; ++tt) {
            const int t = th * 2 + tt;
            float bv = bias[t * 16 + c];
            f32x4 a0 = {bv, bv, bv, bv};
            a0 = __builtin_amdgcn_mfma_f32_16x16x32_bf16(a_agg[0], wfrag[(((0*4+t)*2+0)*4+q)*16+c], a0, 0, 0, 0);
            a0 = __builtin_amdgcn_mfma_f32_16x16x32_bf16(a_agg[1], wfrag[(((0*4+t)*2+1)*4+q)*16+c], a0, 0, 0, 0);
            a0 = __builtin_amdgcn_mfma_f32_16x16x32_bf16(a_x[0],   wfrag[(((1*4+t)*2+0)*4+q)*16+c], a0, 0, 0, 0);
            a0 = __builtin_amdgcn_mfma_f32_16x16x32_bf16(a_x[1],   wfrag[(((1*4+t)*2+1)*4+q)*16+c], a0, 0, 0, 0);
            acc4[tt] = a0;
        }

        if (pool) {
            int nlast = n0 + 15;
            int b0 = batch[min(n0, N_NODES - 1)];
            int b15 = (nlast < N_NODES) ? batch[nlast] : -1;
            if (b0 == b15) {
#pragma unroll
                for (int tt = 0; tt < 2; ++tt) {
                    const int t = th * 2 + tt;
                    float s = acc4[tt][0] + acc4[tt][1] + acc4[tt][2] + acc4[tt][3];
                    s += __shfl_xor(s, 16);
                    s += __shfl_xor(s, 32);
                    if (q == 0) atomicAdd(&sums[b0 * 64 + t * 16 + c], s);
                }
            } else {
#pragma unroll
                for (int r = 0; r < 4; ++r) {
                    int n = n0 + q * 4 + r;
                    if (n < N_NODES) {
                        int bq = batch[n];
#pragma unroll
                        for (int tt = 0; tt < 2; ++tt)
                            atomicAdd(&sums[bq * 64 + (th * 2 + tt) * 16 + c], acc4[tt][r]);
                    }
                }
            }
        } else {
            __syncthreads();   // pair partner done reading A from agg_lds
#pragma unroll
            for (int tt = 0; tt < 2; ++tt) {
                const int t = th * 2 + tt;
#pragma unroll
                for (int r = 0; r < 4; ++r) {
                    float v = acc4[tt][r];
                    if (relu) v = fmaxf(v, 0.f);
                    agg_lds[ng * 16 + q * 4 + r][t * 16 + c] = (unsigned short)bf16rne(v);
                }
            }
            __syncthreads();   // rows assembled across the pair
            int row = w * 8 + (lane >> 3);
            int ch = (lane & 7) * 8;
            int n = g0 + row;
            if (n < N_NODES) {
                short8 v = *(const short8*)&agg_lds[row][ch];
                *(short8*)(hout + (size_t)n * 64 + ch) = v;
            }
        }
    }
}

// ---- the persistent cooperative kernel: all 7 phases, 6 grid syncs ------
__global__ void __launch_bounds__(256) mega_kernel(MegaArgs a) {
    __shared__ __align__(16) char smem[21504];
    cg::grid_group grid = cg::this_grid();
    const int tid = threadIdx.x;
    const int bid = blockIdx.x;
    const int gsz = gridDim.x;

    // ---- P0: zero gcursor (must precede bucket atomics) ----
    if (bid == 0 && tid < NP) a.gcursor[tid] = 0;
    __threadfence();
    grid.sync();

    // ---- P1: bucket chunks (heavy, first) || cvt || gstart || sums-zero --
    {
        const int NC = a.nchunk;
        for (int vb = bid; vb < NC + NCVT + NP; vb += gsz) {
            if (vb < NC) {
                int* hist  = (int*)smem;
                int* scp   = (int*)(smem + 1024);
                int* basep = (int*)(smem + 2048);
                int* cnt2  = (int*)(smem + 3072);
                int* sc    = (int*)(smem + 4096);
                unsigned* stag = (unsigned*)(smem + 5120);
                const int e0 = vb * EPA;
                const int e1 = min(e0 + EPA, a.E);
                __syncthreads();
                for (int i = tid; i < NP; i += 256) { hist[i] = 0; cnt2[i] = 0; }
                __syncthreads();
                for (int e = e0 + tid; e < e1; e += 256)
                    atomicAdd(&hist[a.dst[e] >> 8], 1);
                __syncthreads();
                sc[tid] = (tid < NP) ? hist[tid] : 0;
                __syncthreads();
                for (int off = 1; off < 256; off <<= 1) {
                    int add = (tid >= off) ? sc[tid - off] : 0;
                    __syncthreads();
                    sc[tid] += add;
                    __syncthreads();
                }
                if (tid < NP) {
                    scp[tid] = sc[tid] - hist[tid];
                    if (hist[tid] > 0) basep[tid] = atomicAdd(&a.gcursor[tid], hist[tid]);
                }
                __syncthreads();
                for (int e = e0 + tid; e < e1; e += 256) {
                    int d = a.dst[e], s = a.src[e];
                    int pp = d >> 8;
                    int idx = scp[pp] + atomicAdd(&cnt2[pp], 1);
                    stag[idx] = (unsigned)s | ((unsigned)(d & 255) << 16) | ((unsigned)pp << 24);
                }
                __syncthreads();
                const int n = e1 - e0;
                for (int i = tid; i < n; i += 256) {
                    unsigned v = stag[i];
                    int pp = v >> 24;
                    a.packed[(size_t)pp * PCAP + basep[pp] + (i - scp[pp])] = v & 0x00FFFFFFu;
                }
            } else if (vb < NC + NCVT) {
                int u = vb - NC;
                if (u < 32) a.sums[u * 256 + tid] = 0.f;    // 8192 floats
                int i = u * 256 + tid;
                if (i < N_NODES * 16) {
                    float4 v = ((const float4*)a.x)[i];
                    uint2 o;
                    o.x = pack_bf16x2(v.x, v.y);
                    o.y = pack_bf16x2(v.z, v.w);
                    ((uint2*)a.xb)[i] = o;
                }
            } else {
                int v = vb - NC - NCVT;
                int node = v * 256 + tid;
                if (node < N_NODES) {
                    int b = a.batch[node];
                    int bp = (node > 0) ? a.batch[node - 1] : -1;
                    for (int g = bp + 1; g <= b; ++g) a.gstart[g] = node;
                    if (node == N_NODES - 1)
                        for (int g = b + 1; g <= N_GRAPHS; ++g) a.gstart[g] = N_NODES;
                }
            }
        }
    }
    __threadfence();
    grid.sync();

    // ---- P2: build (196 partitions) ----
    for (int vb = bid; vb < NP; vb += gsz) {
        int* hist = (int*)smem;
        int* lofs = (int*)(smem + 1024);
        int* cnt  = (int*)(smem + 2048);
        int* sc   = (int*)(smem + 3072);
        int* gv   = (int*)(smem + 4096);
        unsigned short* lcsr = (unsigned short*)(smem + 5120);
        const int p = vb;
        __syncthreads();
        int v = (tid < NP) ? a.gcursor[tid] : 0;
        sc[tid] = v; gv[tid] = v;
        __syncthreads();
        for (int off = 1; off < 256; off <<= 1) {
            int add = (tid >= off) ? sc[tid - off] : 0;
            __syncthreads();
            sc[tid] += add;
            __syncthreads();
        }
        const int pb = sc[p] - gv[p];
        const int ne = gv[p];
        if (p == NP - 1 && tid == 0) a.offsets[N_NODES] = sc[NP - 1];
        __syncthreads();
        const unsigned* mypk = a.packed + (size_t)p * PCAP;
        hist[tid] = 0; cnt[tid] = 0;
        __syncthreads();
        for (int i = tid; i < ne; i += 256)
            atomicAdd(&hist[(mypk[i] >> 16) & 255], 1);
        __syncthreads();
        sc[tid] = hist[tid];
        __syncthreads();
        for (int off = 1; off < 256; off <<= 1) {
            int add = (tid >= off) ? sc[tid - off] : 0;
            __syncthreads();
            sc[tid] += add;
            __syncthreads();
        }
        lofs[tid] = sc[tid] - hist[tid];
        int node = p * 256 + tid;
        if (node < N_NODES) a.offsets[node] = pb + lofs[tid];
        __syncthreads();
        for (int i = tid; i < ne; i += 256) {
            unsigned vv = mypk[i];
            int dl = (vv >> 16) & 255;
            int slot = lofs[dl] + atomicAdd(&cnt[dl], 1);
            lcsr[slot] = (unsigned short)(vv & 0xFFFFu);
        }
        __syncthreads();
        for (int i = tid; i < ne; i += 256) a.csr[pb + i] = lcsr[i];
        __syncthreads();
    }
    __threadfence();
    grid.sync();

    // ---- P3..P5: the three fused layers ----
    layer_phase(smem, a.xb, a.offsets, a.csr, a.W1r, a.b1, a.W1o, a.h1, a.batch, a.sums, 1, 0);
    __threadfence();
    grid.sync();
    layer_phase(smem, a.h1, a.offsets, a.csr, a.W2r, a.b2, a.W2o, a.h2, a.batch, a.sums, 1, 0);
    __threadfence();
    grid.sync();
    layer_phase(smem, a.h2, a.offsets, a.csr, a.W3r, a.b3, a.W3o, a.h1, a.batch, a.sums, 0, 1);
    __threadfence();
    grid.sync();

    // ---- P6: final (4 graphs per block, one per wave; shfl-based) ----
    for (int vb = bid; vb < N_GRAPHS / 4; vb += gsz) {
        const int w = tid >> 6, lane = tid & 63;
        int g = vb * 4 + w;
        float cdiv = fmaxf((float)(a.gstart[g + 1] - a.gstart[g]), 1.0f);
        float pv = a.sums[g * 64 + lane] / cdiv;
        a.out[g * 64 + lane] = pv;
        float o = (lane < N_CLASSES) ? a.bl[lane] : 0.f;
#pragma unroll
        for (int k = 0; k < 64; ++k) {
            float pk = __shfl(pv, k);
            if (lane < N_CLASSES) o += pk * a.Wl[lane * 64 + k];
        }
        if (lane < N_CLASSES) a.out[N_GRAPHS * 64 + g * N_CLASSES + lane] = o;
    }
}

// ---------------- Launch: ONE cooperative dispatch ----------------

extern "C" void kernel_launch(void* const* d_in, const int* in_sizes, int n_in,
                              void* d_out, int out_size, void* d_ws, size_t ws_size,
                              hipStream_t stream) {
    const float* x     = (const float*)d_in[0];
    const int*   ei    = (const int*)d_in[1];
    const int*   batch = (const int*)d_in[2];

    const int E = in_sizes[1] / 2;

    char* p = (char*)d_ws;
    unsigned short* xb  = (unsigned short*)p; p += (size_t)N_NODES * 64 * 2;
    unsigned short* h1  = (unsigned short*)p; p += (size_t)N_NODES * 64 * 2;
    unsigned short* h2  = (unsigned short*)p; p += (size_t)N_NODES * 64 * 2;
    unsigned* packed    = (unsigned*)p; p += (size_t)NP * PCAP * 4;
    unsigned short* csr = (unsigned short*)p; p += (size_t)E * 2;
    int* offsets   = (int*)p;   p += (size_t)(N_NODES + 1) * 4;
    int* gcursor   = (int*)p;   p += NP * 4;
    float* sums    = (float*)p; p += (size_t)N_GRAPHS * 64 * 4;
    int* gstart    = (int*)p;   p += (N_GRAPHS + 1) * 4;

    MegaArgs ha;
    ha.x = x; ha.src = ei; ha.dst = ei + E; ha.batch = batch;
    ha.W1r = (const float*)d_in[3];  ha.b1 = (const float*)d_in[4];  ha.W1o = (const float*)d_in[5];
    ha.W2r = (const float*)d_in[6];  ha.b2 = (const float*)d_in[7];  ha.W2o = (const float*)d_in[8];
    ha.W3r = (const float*)d_in[9];  ha.b3 = (const float*)d_in[10]; ha.W3o = (const float*)d_in[11];
    ha.Wl  = (const float*)d_in[12]; ha.bl = (const float*)d_in[13];
    ha.xb = xb; ha.h1 = h1; ha.h2 = h2;
    ha.packed = packed; ha.csr = csr; ha.offsets = offsets; ha.gcursor = gcursor;
    ha.sums = sums; ha.gstart = gstart; ha.out = (float*)d_out;
    ha.E = E; ha.nchunk = (E + EPA - 1) / EPA;

    int nb = 0;
    hipOccupancyMaxActiveBlocksPerMultiprocessor(&nb, mega_kernel, 256, 0);
    if (nb < 1) nb = 1;
    int grid = nb * 256;                 // 256 CUs on MI355X
    if (grid > 1568) grid = 1568;        // largest phase needs 1563 units

    void* args[] = { (void*)&ha };
    hipLaunchCooperativeKernel(mega_kernel, dim3(grid), dim3(256), args, 0, stream);
}

// Round 12
// 234.229 us; speedup vs baseline: 3.8778x; 3.8778x over previous
//
#include <hip/hip_runtime.h>

#define N_NODES   50000
#define HID       64
#define N_GRAPHS  128
#define N_CLASSES 10
#define NP        196           // partitions of 256 nodes (196*256 = 50176)
#define EPA       8192          // edges per bucket block (r0-proven)
#define PCAP      8192          // per-partition capacity in packed[] (>20 sigma)

typedef __attribute__((ext_vector_type(8))) short short8;
typedef __attribute__((ext_vector_type(4))) float f32x4;

__device__ __forceinline__ unsigned bf16rne(float f) {
    unsigned u = __float_as_uint(f);
    return (u + 0x7fffu + ((u >> 16) & 1u)) >> 16;
}
__device__ __forceinline__ unsigned pack_bf16x2(float lo, float hi) {
    return bf16rne(lo) | (bf16rne(hi) << 16);
}

// Features are row-major bf16 [node][64] (r6-proven fastest layout).
// This is the r7 best-measured configuration (234.2 us), reverted verbatim
// after the r11 cooperative-kernel experiment (grid.sync spin ~= 200us/sync,
// 908us total — kernel-boundary drains are far cheaper than grid barriers).

// ---------------- x -> bf16 conversion + gcursor zero + gstart ------------

__global__ void cvt_kernel(const float* __restrict__ x, unsigned short* __restrict__ xb,
                           int* __restrict__ gcursor, const int* __restrict__ batch,
                           int* __restrict__ gstart) {
    int i = blockIdx.x * blockDim.x + threadIdx.x;
    if (blockIdx.x == 0 && threadIdx.x < NP) gcursor[threadIdx.x] = 0;
    if (i < N_NODES) {
        int b = batch[i];
        int bp = (i > 0) ? batch[i - 1] : -1;
        for (int g = bp + 1; g <= b; ++g) gstart[g] = i;       // ~128 writes total
        if (i == N_NODES - 1)
            for (int g = b + 1; g <= N_GRAPHS; ++g) gstart[g] = N_NODES;
    }
    if (i < N_NODES * 16) {
        float4 v = ((const float4*)x)[i];
        uint2 o;
        o.x = pack_bf16x2(v.x, v.y);
        o.y = pack_bf16x2(v.z, v.w);
        ((uint2*)xb)[i] = o;
    }
}

// ---------------- CSR build: 2-level LDS-staged counting sort -------------
// (r2 lesson: flat atomic scatter = 90us of random-RMW; keep the LDS sort.)

__global__ __launch_bounds__(256) void bucket_kernel(
    const int* __restrict__ src, const int* __restrict__ dst,
    int* __restrict__ gcursor, unsigned* __restrict__ packed, int E) {
    __shared__ int hist[NP], scp[NP], base[NP], cnt2[NP];
    __shared__ int sc[256];
    __shared__ unsigned stag[EPA];
    const int t = threadIdx.x;
    const int e0 = blockIdx.x * EPA;
    const int e1 = min(e0 + EPA, E);
    for (int i = t; i < NP; i += 256) { hist[i] = 0; cnt2[i] = 0; }
    __syncthreads();
    for (int e = e0 + t; e < e1; e += 256)
        atomicAdd(&hist[dst[e] >> 8], 1);
    __syncthreads();
    sc[t] = (t < NP) ? hist[t] : 0;
    __syncthreads();
    for (int off = 1; off < 256; off <<= 1) {
        int add = (t >= off) ? sc[t - off] : 0;
        __syncthreads();
        sc[t] += add;
        __syncthreads();
    }
    if (t < NP) {
        scp[t] = sc[t] - hist[t];
        if (hist[t] > 0) base[t] = atomicAdd(&gcursor[t], hist[t]);
    }
    __syncthreads();
    for (int e = e0 + t; e < e1; e += 256) {
        int d = dst[e], s = src[e];
        int p = d >> 8;
        int idx = scp[p] + atomicAdd(&cnt2[p], 1);
        stag[idx] = (unsigned)s | ((unsigned)(d & 255) << 16) | ((unsigned)p << 24);
    }
    __syncthreads();
    const int n = e1 - e0;
    for (int i = t; i < n; i += 256) {
        unsigned v = stag[i];
        int p = v >> 24;
        packed[(size_t)p * PCAP + base[p] + (i - scp[p])] = v & 0x00FFFFFFu;
    }
}

// One block per partition. Integrated pscan, node offsets, LDS csr scatter,
// coalesced copy out. Block 0 also zeroes sums for the fused pooling.
__global__ __launch_bounds__(256) void build_kernel(
    const unsigned* __restrict__ packed, const int* __restrict__ gcursor,
    int* __restrict__ offsets, unsigned short* __restrict__ csr,
    int* __restrict__ sums_zero) {
    __shared__ int hist[256], lofs[256], cnt[256], sc[256], gv[256];
    __shared__ unsigned short lcsr[PCAP];
    const int p = blockIdx.x, t = threadIdx.x;

    if (p == 0) {   // zero sums(128*64 f32) for layer3's fused pooling
        for (int i = t; i < N_GRAPHS * 64; i += 256) sums_zero[i] = 0;
    }

    int v = (t < NP) ? gcursor[t] : 0;
    sc[t] = v; gv[t] = v;
    __syncthreads();
    for (int off = 1; off < 256; off <<= 1) {
        int add = (t >= off) ? sc[t - off] : 0;
        __syncthreads();
        sc[t] += add;
        __syncthreads();
    }
    const int pb = sc[p] - gv[p];          // exclusive prefix at p
    const int ne = gv[p];
    if (p == NP - 1 && t == 0) offsets[N_NODES] = sc[NP - 1];
    __syncthreads();

    const unsigned* mypk = packed + (size_t)p * PCAP;
    hist[t] = 0; cnt[t] = 0;
    __syncthreads();
    for (int i = t; i < ne; i += 256)
        atomicAdd(&hist[(mypk[i] >> 16) & 255], 1);
    __syncthreads();
    sc[t] = hist[t];
    __syncthreads();
    for (int off = 1; off < 256; off <<= 1) {
        int add = (t >= off) ? sc[t - off] : 0;
        __syncthreads();
        sc[t] += add;
        __syncthreads();
    }
    lofs[t] = sc[t] - hist[t];
    int node = p * 256 + t;
    if (node < N_NODES) offsets[node] = pb + lofs[t];
    __syncthreads();
    for (int i = t; i < ne; i += 256) {
        unsigned vv = mypk[i];
        int dl = (vv >> 16) & 255;
        int slot = lofs[dl] + atomicAdd(&cnt[dl], 1);
        lcsr[slot] = (unsigned short)(vv & 0xFFFFu);
    }
    __syncthreads();
    for (int i = t; i < ne; i += 256) csr[pb + i] = lcsr[i];
}

// ---------------- Fused layer: 32 nodes/block, wave-pair MFMA ------------
// 4 waves x 8 nodes gather (1563 blocks, ~24 waves/CU — the measured
// occupancy sweet spot; 16-node blocks regressed in r8). MFMA: waves pair
// up, both read the same 16-row A (agg via LDS), each computes half the
// output channels. Layer is fetch-bound (~33MB L2-miss/layer, r9 PMC) —
// address-count, in-wave MLP, pipelining, and cache-slab levers all null.

template <int RELU, int POOL>
__global__ __launch_bounds__(256) void layer_kernel(
    const unsigned short* __restrict__ hin,
    const int* __restrict__ offsets, const unsigned short* __restrict__ csr_src,
    const float* __restrict__ Wrel, const float* __restrict__ bias,
    const float* __restrict__ Wroot, unsigned short* __restrict__ hout,
    const int* __restrict__ batch, float* __restrict__ sums) {
    __shared__ short8 wfrag[2][4][2][4][16];       // [mat][t][s][q][c], 16KB
    __shared__ unsigned short agg_lds[32][72];     // gather out / outT reuse

    const int tid = threadIdx.x;
    const int w = tid >> 6, lane = tid & 63;
    const int g0 = blockIdx.x * 32;                // block's first node

    // ---- stage weight fragments to LDS (all waves participate) ----
    for (int f = tid; f < 1024; f += 256) {
        int m = f >> 9;
        int r = f & 511;
        int t = r >> 7, s = (r >> 6) & 1, q = (r >> 4) & 3, c = r & 15;
        const float* W = m ? Wroot : Wrel;
        const float4* pw = (const float4*)(W + (t * 16 + c) * 64 + s * 32 + q * 8);
        float4 v0 = pw[0], v1 = pw[1];
        short8 fr;
        fr[0] = (short)bf16rne(v0.x); fr[1] = (short)bf16rne(v0.y);
        fr[2] = (short)bf16rne(v0.z); fr[3] = (short)bf16rne(v0.w);
        fr[4] = (short)bf16rne(v1.x); fr[5] = (short)bf16rne(v1.y);
        fr[6] = (short)bf16rne(v1.z); fr[7] = (short)bf16rne(v1.w);
        wfrag[m][t][s][q][c] = fr;
    }

    // ---- gather phase: each wave owns 8 nodes (r5-proven 1-node body) ----
    {
        const int rg = lane >> 3;          // row group: 8 rows per load instr
        const int cg = lane & 7;           // channel group: 8 ch (16 B)
        const int nb = g0 + w * 8;         // wave's first node
        int myoff = (lane < 9) ? offsets[min(nb + lane, N_NODES)] : 0;
        for (int i = 0; i < 8; ++i) {
            const int beg = __shfl(myoff, i), end = __shfl(myoff, i + 1);
            float acc[8] = {0.f, 0.f, 0.f, 0.f, 0.f, 0.f, 0.f, 0.f};
            for (int base = beg; base < end; base += 64) {
                int cnt = min(64, end - base);
                int sidx = (base + lane < end) ? (int)csr_src[base + lane] : 0;
                for (int kb = 0; kb < cnt; kb += 32) {
                    uint4 u[4];
#pragma unroll
                    for (int p = 0; p < 4; ++p) {
                        int e = kb + 8 * p + rg;
                        int r = __shfl(sidx, e);
                        u[p] = (e < cnt) ? *((const uint4*)(hin + (size_t)r * 64) + cg)
                                         : make_uint4(0u, 0u, 0u, 0u);
                    }
#pragma unroll
                    for (int p = 0; p < 4; ++p) {
                        acc[0] += __uint_as_float(u[p].x << 16);
                        acc[1] += __uint_as_float(u[p].x & 0xffff0000u);
                        acc[2] += __uint_as_float(u[p].y << 16);
                        acc[3] += __uint_as_float(u[p].y & 0xffff0000u);
                        acc[4] += __uint_as_float(u[p].z << 16);
                        acc[5] += __uint_as_float(u[p].z & 0xffff0000u);
                        acc[6] += __uint_as_float(u[p].w << 16);
                        acc[7] += __uint_as_float(u[p].w & 0xffff0000u);
                    }
                }
            }
#pragma unroll
            for (int m = 8; m <= 32; m <<= 1)
#pragma unroll
                for (int j = 0; j < 8; ++j)
                    acc[j] += __shfl_xor(acc[j], m);
            if (rg == 0) {
                uint4 o;
                o.x = pack_bf16x2(acc[0], acc[1]);
                o.y = pack_bf16x2(acc[2], acc[3]);
                o.z = pack_bf16x2(acc[4], acc[5]);
                o.w = pack_bf16x2(acc[6], acc[7]);
                *((uint4*)&agg_lds[w * 8 + i][cg * 8]) = o;
            }
        }
    }

    __syncthreads();                       // wfrag + cross-wave agg ready

    // ---- linear phase: wave-pair shares A, splits output channels ----
    const int ng = w >> 1;                 // node group: rows ng*16..+15
    const int th = w & 1;                  // t-half: t = th*2 + {0,1}
    const int q = lane >> 4, c = lane & 15;
    const int n0 = g0 + ng * 16;

    short8 a_agg[2], a_x[2];
#pragma unroll
    for (int s = 0; s < 2; ++s) {
        a_agg[s] = *(const short8*)&agg_lds[ng * 16 + c][s * 32 + q * 8];
        a_x[s]   = *(const short8*)(hin + (size_t)min(n0 + c, N_NODES - 1) * 64 + s * 32 + q * 8);
    }

    f32x4 acc4[2];
#pragma unroll
    for (int tt = 0; tt < 2; ++tt) {
        const int t = th * 2 + tt;
        float bv = bias[t * 16 + c];
        f32x4 a0 = {bv, bv, bv, bv};
        a0 = __builtin_amdgcn_mfma_f32_16x16x32_bf16(a_agg[0], wfrag[0][t][0][q][c], a0, 0, 0, 0);
        a0 = __builtin_amdgcn_mfma_f32_16x16x32_bf16(a_agg[1], wfrag[0][t][1][q][c], a0, 0, 0, 0);
        a0 = __builtin_amdgcn_mfma_f32_16x16x32_bf16(a_x[0],   wfrag[1][t][0][q][c], a0, 0, 0, 0);
        a0 = __builtin_amdgcn_mfma_f32_16x16x32_bf16(a_x[1],   wfrag[1][t][1][q][c], a0, 0, 0, 0);
        acc4[tt] = a0;
    }

    if (POOL) {
        // batch sorted: 16-node group almost always one graph
        int nlast = n0 + 15;
        int b0 = batch[min(n0, N_NODES - 1)];
        int b15 = (nlast < N_NODES) ? batch[nlast] : -1;
        if (b0 == b15) {
#pragma unroll
            for (int tt = 0; tt < 2; ++tt) {
                const int t = th * 2 + tt;
                float s = acc4[tt][0] + acc4[tt][1] + acc4[tt][2] + acc4[tt][3];
                s += __shfl_xor(s, 16);          // sum over q (lane bits 4-5)
                s += __shfl_xor(s, 32);
                if (q == 0) atomicAdd(&sums[b0 * 64 + t * 16 + c], s);
            }
        } else {                                  // boundary / tail waves
#pragma unroll
            for (int r = 0; r < 4; ++r) {
                int n = n0 + q * 4 + r;
                if (n < N_NODES) {
                    int bq = batch[n];
#pragma unroll
                    for (int tt = 0; tt < 2; ++tt)
                        atomicAdd(&sums[bq * 64 + (th * 2 + tt) * 16 + c], acc4[tt][r]);
                }
            }
        }
    } else {
        __syncthreads();   // pair partner done reading A from agg_lds
        // ReLU + bf16 transpose into agg_lds (rows=node, ch=t*16+c)
#pragma unroll
        for (int tt = 0; tt < 2; ++tt) {
            const int t = th * 2 + tt;
#pragma unroll
            for (int r = 0; r < 4; ++r) {
                float v = acc4[tt][r];
                if (RELU) v = fmaxf(v, 0.f);
                agg_lds[ng * 16 + q * 4 + r][t * 16 + c] = (unsigned short)bf16rne(v);
            }
        }
        __syncthreads();   // rows assembled across the pair
        // store: wave w writes rows w*8..w*8+7, full 64 ch, short8
        {
            int row = w * 8 + (lane >> 3);
            int ch = (lane & 7) * 8;
            int n = g0 + row;
            if (n < N_NODES) {
                short8 v = *(const short8*)&agg_lds[row][ch];
                *(short8*)(hout + (size_t)n * 64 + ch) = v;
            }
        }
    }
}

// ---------------- Final: counts from gstart (no binary search) ------------

__global__ void final_kernel(const float* __restrict__ sums, const int* __restrict__ gstart,
                             const float* __restrict__ Wlin, const float* __restrict__ blin,
                             float* __restrict__ out) {
    __shared__ float pl[64];
    int g = blockIdx.x, lane = threadIdx.x;
    float cdiv = fmaxf((float)(gstart[g + 1] - gstart[g]), 1.0f);
    float p = sums[g * 64 + lane] / cdiv;
    out[g * 64 + lane] = p;               // pooled output
    pl[lane] = p;
    __syncthreads();
    if (lane < N_CLASSES) {
        float o = blin[lane];
#pragma unroll
        for (int k = 0; k < 64; ++k) o += pl[k] * Wlin[lane * 64 + k];
        out[N_GRAPHS * 64 + g * N_CLASSES + lane] = o;  // classifier output
    }
}

// ---------------- Launch (7 dispatches, no memsets) ----------------

extern "C" void kernel_launch(void* const* d_in, const int* in_sizes, int n_in,
                              void* d_out, int out_size, void* d_ws, size_t ws_size,
                              hipStream_t stream) {
    const float* x     = (const float*)d_in[0];
    const int*   ei    = (const int*)d_in[1];
    const int*   batch = (const int*)d_in[2];
    const float* W1r = (const float*)d_in[3];
    const float* b1  = (const float*)d_in[4];
    const float* W1o = (const float*)d_in[5];
    const float* W2r = (const float*)d_in[6];
    const float* b2  = (const float*)d_in[7];
    const float* W2o = (const float*)d_in[8];
    const float* W3r = (const float*)d_in[9];
    const float* b3  = (const float*)d_in[10];
    const float* W3o = (const float*)d_in[11];
    const float* Wl  = (const float*)d_in[12];
    const float* bl  = (const float*)d_in[13];
    float* out = (float*)d_out;

    const int E = in_sizes[1] / 2;
    const int* src = ei;
    const int* dst = ei + E;

    char* p = (char*)d_ws;
    unsigned short* xb  = (unsigned short*)p; p += (size_t)N_NODES * 64 * 2;
    unsigned short* h1  = (unsigned short*)p; p += (size_t)N_NODES * 64 * 2;
    unsigned short* h2  = (unsigned short*)p; p += (size_t)N_NODES * 64 * 2;
    unsigned* packed    = (unsigned*)p; p += (size_t)NP * PCAP * 4;
    unsigned short* csr = (unsigned short*)p; p += (size_t)E * 2;
    int* offsets   = (int*)p;   p += (size_t)(N_NODES + 1) * 4;
    int* gcursor   = (int*)p;   p += NP * 4;
    float* sums    = (float*)p; p += (size_t)N_GRAPHS * 64 * 4;
    int* gstart    = (int*)p;   p += (N_GRAPHS + 1) * 4;

    const int NCHUNK = (E + EPA - 1) / EPA;  // 153
    cvt_kernel<<<(N_NODES * 16 + 255) / 256, 256, 0, stream>>>(x, xb, gcursor, batch, gstart);
    bucket_kernel<<<NCHUNK, 256, 0, stream>>>(src, dst, gcursor, packed, E);
    build_kernel<<<NP, 256, 0, stream>>>(packed, gcursor, offsets, csr, (int*)sums);

    const int LB = (N_NODES + 31) / 32;    // 1563 blocks, 4 waves x 8 nodes
    layer_kernel<1, 0><<<LB, 256, 0, stream>>>(xb, offsets, csr, W1r, b1, W1o, h1, batch, sums);
    layer_kernel<1, 0><<<LB, 256, 0, stream>>>(h1, offsets, csr, W2r, b2, W2o, h2, batch, sums);
    layer_kernel<0, 1><<<LB, 256, 0, stream>>>(h2, offsets, csr, W3r, b3, W3o, h1, batch, sums);

    final_kernel<<<N_GRAPHS, 64, 0, stream>>>(sums, gstart, Wl, bl, out);
}